// Round 12
// baseline (2275.651 us; speedup 1.0000x reference)
//
#include <hip/hip_runtime.h>
#include <math.h>

// ---- problem constants ----
#define C_      3
#define H_      224
#define W_      224
#define KH_     14
#define KW_     14
#define NPATCH  196
#define PELEMS  768
#define D_      768
#define HEADS_  12
#define Y_      64
#define MHID    3072
#define NMASK   100
#define NSTEPS  12
#define ALPHA_  0.1f
#define BETA_   0.125f
#define EPS_    1e-5f
#define B_      16
#define NTOK    197
#define ROWS    (B_*NTOK)   /* 3152 real rows */
#define MPAD    3200        /* 50 * 64 */
#define QKLD    1536        /* fused q|k leading dim */
#define PACKLD  4608        /* hid(3072) | Gq(768) | Gk(768) */
#define W2LD    4608        /* qk(1536) | hid(3072) fused B rows */
#define PMP     228         /* LDS P pitch (fp32) */
#define PPITCH  224         /* global P/PT/kT/qT pitch (bf16), 7*32 */
#define KSPLIT  4           /* grad GEMM split-K (4608/4=1152=18*64) */

typedef short short8 __attribute__((ext_vector_type(8)));
typedef unsigned short ushort8 __attribute__((ext_vector_type(8)));
typedef float floatx4 __attribute__((ext_vector_type(4)));

__device__ __forceinline__ unsigned short f2bf(float f) {
    union { float f; unsigned u; } v; v.f = f;
    unsigned r = (v.u + 0x7FFFu + ((v.u >> 16) & 1u)) >> 16;
    return (unsigned short)r;
}
__device__ __forceinline__ float bf2f(unsigned short u) {
    union { unsigned u; float f; } v; v.u = ((unsigned)u) << 16;
    return v.f;
}

__device__ __forceinline__ void async_cp16(const void* g, void* l) {
    __builtin_amdgcn_global_load_lds(
        (const __attribute__((address_space(1))) unsigned int*)g,
        (__attribute__((address_space(3))) unsigned int*)l, 16, 0, 0);
}

// ---------------------------------------------------------------------------
// MFMA bf16 NT GEMM: C[M][N] = A(MxK bf16) @ B(NxK bf16)^T.
// 64x128 tile, BK=64/iter, global_load_lds staging (r10 proven; register
// prefetch spills to scratch — r8; 128x128 tile is grid-starved — r7-r9).
// OUT_MODE: 0 = fp32 store, 1 = bf16 store,
//           3 = split epilogue: col<1536 -> Cout bf16 (ld QKLD), else relu ->
//               Cout2 bf16 (ld PACKLD, col-1536). 1D grid with temporal
//               column-group swizzle (6 col-tiles x 50 row-tiles per group)
//               to shrink the resident window's B working set (L2 thrash fix).
//           4 = split-K: koff = blockIdx.z*K, atomicAdd(Cout, ALPHA*v) fp32
template<int OUT_MODE, bool RELU, bool HAS_BIAS>
__global__ __launch_bounds__(256) void mfma_gemm(
    const unsigned short* __restrict__ A, int lda,
    const unsigned short* __restrict__ B, int ldb,
    void* __restrict__ Cout, int ldc, void* __restrict__ Cout2,
    const float* __restrict__ bias, int K)
{
    __shared__ alignas(16) unsigned short ldsA[2][64 * 32];
    __shared__ alignas(16) unsigned short ldsB[2][128 * 32];

    int bx, by;
    int koff = 0;
    if (OUT_MODE == 3) {
        const int GROUP = 6;                 // col-tiles per temporal group
        const int per = GROUP * (MPAD / 64); // 300 blocks per group
        int lin = blockIdx.x;
        int grp = lin / per;
        int rem = lin - grp * per;
        by = rem / GROUP;
        bx = grp * GROUP + rem % GROUP;
    } else {
        bx = blockIdx.x; by = blockIdx.y;
        if (OUT_MODE == 4) koff = blockIdx.z * K;
    }

    const int t    = threadIdx.x;
    const int wave = t >> 6;
    const int lane = t & 63;
    const int row0 = by << 6;
    const int col0 = bx << 7;
    const int wm = (wave & 1) << 5;
    const int wn = (wave >> 1) << 6;
    const int r  = lane & 15;
    const int qd = lane >> 4;

    const unsigned short* Abase = A + (size_t)row0 * lda + koff;
    const unsigned short* Bbase = B + (size_t)col0 * ldb + koff;

    floatx4 acc[2][4];
#pragma unroll
    for (int i = 0; i < 2; ++i)
#pragma unroll
        for (int j = 0; j < 4; ++j)
            acc[i][j] = (floatx4){0.f, 0.f, 0.f, 0.f};

    const int crow = t >> 2;
    const int coff = (t & 3) << 3;
    for (int k0 = 0; k0 < K; k0 += 64) {
#pragma unroll
        for (int kb = 0; kb < 2; ++kb) {
            const int kk = k0 + kb * 32;
            async_cp16(Abase + (size_t)crow * lda + kk + coff,
                       ldsA[kb] + (wave << 9));
            async_cp16(Bbase + (size_t)crow * ldb + kk + coff,
                       ldsB[kb] + (wave << 9));
            async_cp16(Bbase + (size_t)(64 + crow) * ldb + kk + coff,
                       ldsB[kb] + 2048 + (wave << 9));
        }
        __syncthreads();
#pragma unroll
        for (int kb = 0; kb < 2; ++kb) {
            short8 af[2], bfr[4];
#pragma unroll
            for (int i = 0; i < 2; ++i)
                af[i]  = *(const short8*)&ldsA[kb][(wm + (i << 4) + r) * 32 + (qd << 3)];
#pragma unroll
            for (int j = 0; j < 4; ++j)
                bfr[j] = *(const short8*)&ldsB[kb][(wn + (j << 4) + r) * 32 + (qd << 3)];
#pragma unroll
            for (int i = 0; i < 2; ++i)
#pragma unroll
                for (int j = 0; j < 4; ++j)
                    acc[i][j] = __builtin_amdgcn_mfma_f32_16x16x32_bf16(
                                    af[i], bfr[j], acc[i][j], 0, 0, 0);
        }
        __syncthreads();
    }

#pragma unroll
    for (int i = 0; i < 2; ++i) {
#pragma unroll
        for (int j = 0; j < 4; ++j) {
            int cc = col0 + wn + (j << 4) + r;
#pragma unroll
            for (int reg = 0; reg < 4; ++reg) {
                int rr = row0 + wm + (i << 4) + (qd << 2) + reg;
                float v = acc[i][j][reg];
                if (HAS_BIAS) v += bias[cc];
                if (RELU)     v = fmaxf(v, 0.f);
                if (OUT_MODE == 1)
                    ((unsigned short*)Cout)[(size_t)rr * ldc + cc] = f2bf(v);
                else if (OUT_MODE == 3) {
                    if (cc < QKLD)
                        ((unsigned short*)Cout)[(size_t)rr * QKLD + cc] = f2bf(v);
                    else
                        ((unsigned short*)Cout2)[(size_t)rr * PACKLD + (cc - QKLD)]
                            = f2bf(fmaxf(v, 0.f));
                } else if (OUT_MODE == 4)
                    atomicAdd(&((float*)Cout)[(size_t)rr * ldc + cc], ALPHA_ * v);
                else
                    ((float*)Cout)[(size_t)rr * ldc + cc] = v;
            }
        }
    }
}

// ---------------------------------------------------------------------------
// Attention A: per (bh, 32-q-row chunk): S = Q K^T via MFMA, softmax (beta in
// exp), write P[bh][n][m], PT[bh][m][n] (bf16, pitch 224, K-dims zeroed),
// plus the kT[y][m] / qT[y][n] slices for this block's m/n range (folded-in
// transpose: KsS/QcS are already staged; lanes sweep y at fixed m — the
// packed-dword LDS reads are conflict-free).
__global__ __launch_bounds__(256) void attn_pgq_kernel(
    const unsigned short* __restrict__ qk,   // bf16 [MPAD][1536]
    unsigned short* __restrict__ P,          // [192][224][224]
    unsigned short* __restrict__ PT,         // [192][224][224]
    unsigned short* __restrict__ kT,         // [192][64][224]
    unsigned short* __restrict__ qT)         // [192][64][224]
{
    const int bh = blockIdx.x;
    const int h = bh % HEADS_, b = bh / HEADS_;
    const int n0 = blockIdx.y << 5;
    const int csz = (NTOK - n0 < 32) ? (NTOK - n0) : 32;
    const int t = threadIdx.x;
    const int lane = t & 63, wave = t >> 6;
    const int ln15 = lane & 15, quad = lane >> 4;

    __shared__ alignas(16) unsigned short KsS[208 * 72];  // K_h m-major
    __shared__ alignas(16) unsigned short QcS[32 * 72];   // Q chunk
    __shared__ alignas(16) float Pm[32 * PMP];            // S/P fp32

    const size_t rowbase = (size_t)(b * NTOK) * QKLD;
    const int hoff = h * 64;

    for (int idx = t; idx < NTOK * 8; idx += 256) {
        int m = idx >> 3, c8 = idx & 7;
        *(uint4*)&KsS[m * 72 + c8 * 8] =
            *(const uint4*)&qk[rowbase + (size_t)m * QKLD + 768 + hoff + c8 * 8];
    }
    for (int idx = t; idx < 88; idx += 256) {
        int m = 197 + (idx >> 3), c8 = idx & 7;
        *(uint4*)&KsS[m * 72 + c8 * 8] = (uint4){0, 0, 0, 0};
    }
    for (int idx = t; idx < csz * 8; idx += 256) {
        int nn = idx >> 3, c8 = idx & 7;
        *(uint4*)&QcS[nn * 72 + c8 * 8] =
            *(const uint4*)&qk[rowbase + (size_t)(n0 + nn) * QKLD + hoff + c8 * 8];
    }
    __syncthreads();

    // ---- S = Q K^T via MFMA ----
    {
        short8 aq[2][2];
#pragma unroll
        for (int mt = 0; mt < 2; ++mt)
#pragma unroll
            for (int kb = 0; kb < 2; ++kb)
                aq[mt][kb] = *(const short8*)
                    &QcS[(mt * 16 + ln15) * 72 + kb * 32 + quad * 8];

        for (int nt = wave; nt < 13; nt += 4) {
            short8 b0 = *(const short8*)&KsS[(nt * 16 + ln15) * 72 + quad * 8];
            short8 b1 = *(const short8*)&KsS[(nt * 16 + ln15) * 72 + 32 + quad * 8];
            floatx4 s0 = (floatx4){0.f, 0.f, 0.f, 0.f};
            floatx4 s1 = (floatx4){0.f, 0.f, 0.f, 0.f};
            s0 = __builtin_amdgcn_mfma_f32_16x16x32_bf16(aq[0][0], b0, s0, 0, 0, 0);
            s0 = __builtin_amdgcn_mfma_f32_16x16x32_bf16(aq[0][1], b1, s0, 0, 0, 0);
            s1 = __builtin_amdgcn_mfma_f32_16x16x32_bf16(aq[1][0], b0, s1, 0, 0, 0);
            s1 = __builtin_amdgcn_mfma_f32_16x16x32_bf16(aq[1][1], b1, s1, 0, 0, 0);
#pragma unroll
            for (int reg = 0; reg < 4; ++reg) {
                Pm[(quad * 4 + reg) * PMP + nt * 16 + ln15]        = s0[reg];
                Pm[(16 + quad * 4 + reg) * PMP + nt * 16 + ln15]   = s1[reg];
            }
        }
    }

    // ---- kT / qT slices (reads staged LDS, independent of Pm) ----
    {
        const int yq = t & 63;
        const int mg = t >> 6;          // 0..3, 8 m each
        unsigned short* kTd = kT + (size_t)bh * 64 * PPITCH + (size_t)yq * PPITCH;
        unsigned short* qTd = qT + (size_t)bh * 64 * PPITCH + (size_t)yq * PPITCH;
#pragma unroll
        for (int c = 0; c < 4; ++c) {
            int mm = n0 + mg * 8 + 2 * c;
            unsigned lo = (mm     < 208) ? (unsigned)KsS[(mm    ) * 72 + yq] : 0u;
            unsigned hi = (mm + 1 < 208) ? (unsigned)KsS[(mm + 1) * 72 + yq] : 0u;
            *(unsigned*)&kTd[mm] = lo | (hi << 16);
        }
#pragma unroll
        for (int c = 0; c < 4; ++c) {
            int nn = mg * 8 + 2 * c;
            unsigned lo = (nn     < csz) ? (unsigned)QcS[(nn    ) * 72 + yq] : 0u;
            unsigned hi = (nn + 1 < csz) ? (unsigned)QcS[(nn + 1) * 72 + yq] : 0u;
            *(unsigned*)&qTd[n0 + nn] = lo | (hi << 16);
        }
    }
    __syncthreads();

    // ---- softmax rows (beta applied inside exp) ----
    for (int nn = wave; nn < csz; nn += 4) {
        float v0 = Pm[nn * PMP + lane];
        float v1 = (lane +  64 < NTOK) ? Pm[nn * PMP + lane +  64] : -1e30f;
        float v2 = (lane + 128 < NTOK) ? Pm[nn * PMP + lane + 128] : -1e30f;
        float v3 = (lane + 192 < NTOK) ? Pm[nn * PMP + lane + 192] : -1e30f;
        float mx = fmaxf(fmaxf(v0, v1), fmaxf(v2, v3));
#pragma unroll
        for (int o = 32; o > 0; o >>= 1) mx = fmaxf(mx, __shfl_xor(mx, o, 64));
        float e0 = __expf((v0 - mx) * BETA_);
        float e1 = (lane +  64 < NTOK) ? __expf((v1 - mx) * BETA_) : 0.f;
        float e2 = (lane + 128 < NTOK) ? __expf((v2 - mx) * BETA_) : 0.f;
        float e3 = (lane + 192 < NTOK) ? __expf((v3 - mx) * BETA_) : 0.f;
        float s = e0 + e1 + e2 + e3;
#pragma unroll
        for (int o = 32; o > 0; o >>= 1) s += __shfl_xor(s, o, 64);
        float inv = 1.0f / s;
        Pm[nn * PMP + lane] = e0 * inv;
        if (lane +  64 < NTOK) Pm[nn * PMP + lane +  64] = e1 * inv;
        if (lane + 128 < NTOK) Pm[nn * PMP + lane + 128] = e2 * inv;
        if (lane + 192 < NTOK) Pm[nn * PMP + lane + 192] = e3 * inv;
    }
    __syncthreads();

    // ---- write P rows (m-pads zero) ----
    if (t < PPITCH) {
        for (int nn = 0; nn < csz; ++nn) {
            unsigned short v = (t < NTOK) ? f2bf(Pm[nn * PMP + t]) : (unsigned short)0;
            P[((size_t)bh * PPITCH + n0 + nn) * PPITCH + t] = v;
        }
    }
    // ---- write PT cols (32-wide n-chunk; nn>=csz and m>=197 zeroed) ----
    if (t < PPITCH) {
        unsigned short* drow = &PT[((size_t)bh * PPITCH + t) * PPITCH + n0];
        bool mreal = (t < NTOK);
#pragma unroll
        for (int c = 0; c < 16; ++c) {
            unsigned lo = (mreal && 2 * c     < csz) ? f2bf(Pm[(2 * c    ) * PMP + t]) : 0u;
            unsigned hi = (mreal && 2 * c + 1 < csz) ? f2bf(Pm[(2 * c + 1) * PMP + t]) : 0u;
            *(unsigned*)&drow[2 * c] = lo | (hi << 16);
        }
    }
}

// ---------------------------------------------------------------------------
// Attention B (MFMA): grid (192, 2, 2).
// sel=0: Gq[n][y] = sum_m P[n][m] kT[y][m]  -> pack cols 3072+
// sel=1: Gk[m][y] = sum_n PT[m][n] qT[y][n] -> pack cols 3840+
__global__ __launch_bounds__(256) void attn_pv_kernel(
    const unsigned short* __restrict__ P,
    const unsigned short* __restrict__ PT,
    const unsigned short* __restrict__ kT,
    const unsigned short* __restrict__ qT,
    unsigned short* __restrict__ pack)
{
    const int bh = blockIdx.x;
    const int h = bh % HEADS_, b = bh / HEADS_;
    const int sel = blockIdx.y;
    const int mbase = blockIdx.z * 112;
    const int t = threadIdx.x;
    const int lane = t & 63, wave = t >> 6;
    const int ln15 = lane & 15, quad = lane >> 4;

    const unsigned short* Abase = (sel ? PT : P) + (size_t)bh * PPITCH * PPITCH;
    const unsigned short* Bv    = (sel ? qT : kT) + (size_t)bh * 64 * PPITCH;
    const int colbase = sel ? 3840 : 3072;

    __shared__ alignas(16) unsigned short Bs[64 * 232];
    for (int idx = t; idx < 64 * 28; idx += 256) {
        int y = idx / 28, c = idx % 28;
        *(uint4*)&Bs[y * 232 + c * 8] = *(const uint4*)&Bv[(size_t)y * PPITCH + c * 8];
    }
    __syncthreads();

    floatx4 acc[7];
#pragma unroll
    for (int i = 0; i < 7; ++i) acc[i] = (floatx4){0.f, 0.f, 0.f, 0.f};

    for (int kb = 0; kb < 7; ++kb) {
        short8 bf = *(const short8*)&Bs[(wave * 16 + ln15) * 232 + kb * 32 + quad * 8];
#pragma unroll
        for (int i = 0; i < 7; ++i) {
            short8 af = *(const short8*)
                &Abase[(size_t)(mbase + i * 16 + ln15) * PPITCH + kb * 32 + quad * 8];
            acc[i] = __builtin_amdgcn_mfma_f32_16x16x32_bf16(af, bf, acc[i], 0, 0, 0);
        }
    }

    const int coln = colbase + h * 64 + wave * 16 + ln15;
#pragma unroll
    for (int i = 0; i < 7; ++i) {
#pragma unroll
        for (int reg = 0; reg < 4; ++reg) {
            int rowm = mbase + i * 16 + quad * 4 + reg;
            if (rowm < NTOK)
                pack[(size_t)(b * NTOK + rowm) * PACKLD + coln] = f2bf(acc[i][reg]);
        }
    }
}

// ---------------------------------------------------------------------------
// setup conversions
__global__ __launch_bounds__(256) void w2pack_kernel(const float* __restrict__ Wq,
                                                     const float* __restrict__ Wk,
                                                     const float* __restrict__ Xi,
                                                     unsigned short* __restrict__ out)
{
    int idx = blockIdx.x * 256 + threadIdx.x;          // n*768 + d
    int d = idx % D_, n = idx / D_;
    float v;
    if (n < 768)       v = Wq[((size_t)(n >> 6) * D_ + d) * Y_ + (n & 63)];
    else if (n < 1536) { int e = n - 768; v = Wk[((size_t)(e >> 6) * D_ + d) * Y_ + (e & 63)]; }
    else               v = Xi[(size_t)d * MHID + (n - 1536)];
    out[idx] = f2bf(v);
}

__global__ __launch_bounds__(256) void bpack_kernel(const float* __restrict__ Xi,
                                                    const float* __restrict__ Wq,
                                                    const float* __restrict__ Wk,
                                                    unsigned short* __restrict__ out)
{
    int idx = blockIdx.x * 256 + threadIdx.x;          // d*4608 + c
    int c = idx % PACKLD, d = idx / PACKLD;
    float v;
    if (c < 3072)       v = Xi[(size_t)d * MHID + c];
    else if (c < 3840)  { int e = c - 3072; v = Wq[((size_t)(e >> 6) * D_ + d) * Y_ + (e & 63)]; }
    else                { int e = c - 3840; v = Wk[((size_t)(e >> 6) * D_ + d) * Y_ + (e & 63)]; }
    out[idx] = f2bf(v);
}

__global__ __launch_bounds__(256) void t768_kernel(const float* __restrict__ in,
                                                   unsigned short* __restrict__ out)
{
    int idx = blockIdx.x * 256 + threadIdx.x;          // n*768 + k
    int k = idx % D_, n = idx / D_;
    out[idx] = f2bf(in[(size_t)k * D_ + n]);
}

// ---------------------------------------------------------------------------
__global__ void mask_flags_kernel(const int* __restrict__ mask, int* __restrict__ flags)
{
    int b = threadIdx.x;
    if (b >= B_) return;
    const int* mb = mask + b * NPATCH;
    int* fb = flags + b * NPATCH;
    int cnt = 0;
    for (int n = 0; n < NPATCH; ++n) {
        int mv = mb[n];
        fb[n] = (mv == 1 && cnt < NMASK) ? 1 : 0;
        cnt += (mv == 1);
    }
    if (cnt < NMASK) fb[0] = 1;
}

__global__ __launch_bounds__(256) void patchify_kernel(const float* __restrict__ img,
                                                       unsigned short* __restrict__ patch)
{
    int idx = blockIdx.x * 256 + threadIdx.x;          // row*768 + e
    int e = idx % PELEMS, row = idx / PELEMS;
    int b = row / NPATCH, n = row % NPATCH;
    int kh = n / KW_, kw = n % KW_;
    int c = e >> 8, p = (e >> 4) & 15, q2 = e & 15;
    patch[idx] = f2bf(img[(((size_t)b * C_ + c) * H_ + kh * 16 + p) * W_ + kw * 16 + q2]);
}

__global__ __launch_bounds__(256) void build_x_kernel(const float* __restrict__ tok,
                                                      const int* __restrict__ flags,
                                                      const float* __restrict__ cls,
                                                      const float* __restrict__ mtok,
                                                      const float* __restrict__ pos,
                                                      float* __restrict__ x)
{
    int row = blockIdx.x;
    int b = row / NTOK, rr = row % NTOK;
    int tid = threadIdx.x;
#pragma unroll
    for (int i = 0; i < 3; ++i) {
        int d = tid + (i << 8);
        float v;
        if (rr == 0) v = cls[d];
        else {
            int n = rr - 1;
            v = flags[b * NPATCH + n] ? mtok[d]
                                      : tok[((size_t)b * NPATCH + n) * D_ + d];
        }
        x[(size_t)row * D_ + d] = v + pos[(size_t)rr * D_ + d];
    }
}

__global__ __launch_bounds__(256) void lnorm_kernel(const float* __restrict__ x,
                                                    unsigned short* __restrict__ g,
                                                    const float* __restrict__ gamma,
                                                    const float* __restrict__ delta)
{
    int row = blockIdx.x, tid = threadIdx.x;
    const float* xr = x + (size_t)row * D_;
    float v0 = xr[tid], v1 = xr[tid + 256], v2 = xr[tid + 512];

    __shared__ float red[256];
    red[tid] = v0 + v1 + v2;
    __syncthreads();
    for (int off = 128; off > 0; off >>= 1) {
        if (tid < off) red[tid] += red[tid + off];
        __syncthreads();
    }
    float mean = red[0] * (1.0f / D_);
    __syncthreads();
    float a0 = v0 - mean, a1 = v1 - mean, a2 = v2 - mean;
    red[tid] = a0 * a0 + a1 * a1 + a2 * a2;
    __syncthreads();
    for (int off = 128; off > 0; off >>= 1) {
        if (tid < off) red[tid] += red[tid + off];
        __syncthreads();
    }
    float var = red[0] * (1.0f / D_);
    float inv = gamma[0] / sqrtf(var + EPS_);
    unsigned short* gr = g + (size_t)row * D_;
    gr[tid]       = f2bf(a0 * inv + delta[tid]);
    gr[tid + 256] = f2bf(a1 * inv + delta[tid + 256]);
    gr[tid + 512] = f2bf(a2 * inv + delta[tid + 512]);
}

// ---------------------------------------------------------------------------
__global__ __launch_bounds__(256) void unpatch_kernel(const float* __restrict__ dec,
                                                      float* __restrict__ out)
{
    int idx = blockIdx.x * 256 + threadIdx.x;
    int ww = idx % W_;
    int t2 = idx / W_;
    int hh = t2 % H_;
    int t3 = t2 / H_;
    int c  = t3 % C_;
    int b  = t3 / C_;
    int kh = hh >> 4, p = hh & 15, kw = ww >> 4, q2 = ww & 15;
    int n = kh * KW_ + kw;
    int e = (c << 8) + (p << 4) + q2;
    out[idx] = dec[((size_t)b * NTOK + 1 + n) * D_ + e];
}

// ---------------------------------------------------------------------------
extern "C" void kernel_launch(void* const* d_in, const int* in_sizes, int n_in,
                              void* d_out, int out_size, void* d_ws, size_t ws_size,
                              hipStream_t stream)
{
    const float* img   = (const float*)d_in[0];
    const int*   mask  = (const int*)d_in[1];
    const float* enc_W = (const float*)d_in[2];
    const float* enc_b = (const float*)d_in[3];
    const float* dec_W = (const float*)d_in[4];
    const float* dec_b = (const float*)d_in[5];
    const float* cls   = (const float*)d_in[6];
    const float* mtok  = (const float*)d_in[7];
    const float* pos   = (const float*)d_in[8];
    const float* Wq    = (const float*)d_in[9];
    const float* Wk    = (const float*)d_in[10];
    const float* Xi    = (const float*)d_in[11];
    const float* gamma = (const float*)d_in[12];
    const float* delta = (const float*)d_in[13];
    float* out = (float*)d_out;

    float* ws = (float*)d_ws;
    size_t off = 0;
    auto alloc = [&](size_t nfloats) {
        off = (off + 63) & ~(size_t)63;
        float* p = ws + off; off += nfloats; return p;
    };
    float*          x    = alloc((size_t)MPAD * D_);                  // fp32
    unsigned short* g    = (unsigned short*)alloc((size_t)MPAD * D_ / 2);
    // qk bf16 [MPAD][1536]; bytes reused as dec fp32 [MPAD][768] at the end
    unsigned short* qkg  = (unsigned short*)alloc((size_t)MPAD * QKLD / 2);
    float*          decb = (float*)qkg;
    unsigned short* pack = (unsigned short*)alloc((size_t)MPAD * PACKLD / 2);
    unsigned short* Pbuf = (unsigned short*)alloc((size_t)192 * PPITCH * PPITCH / 2);
    unsigned short* PTb  = (unsigned short*)alloc((size_t)192 * PPITCH * PPITCH / 2);
    unsigned short* kT   = (unsigned short*)alloc((size_t)192 * 64 * PPITCH / 2);
    unsigned short* qT   = (unsigned short*)alloc((size_t)192 * 64 * PPITCH / 2);
    unsigned short* W2   = (unsigned short*)alloc((size_t)W2LD * D_ / 2);
    unsigned short* Bpk  = (unsigned short*)alloc((size_t)D_ * PACKLD / 2);
    unsigned short* decT = (unsigned short*)alloc((size_t)D_ * D_ / 2);
    unsigned short* encT = (unsigned short*)alloc((size_t)D_ * D_ / 2);
    int*            flags = (int*)alloc(B_ * NPATCH);
    // setup-phase overlays inside pack (dead until first hid GEMM)
    unsigned short* patch = pack;                                // MPAD x 768 bf16
    float*          tok   = (float*)(pack + (size_t)MPAD * D_);  // MPAD x 768 fp32

    const dim3 blk(256);

    // ---- one-time packs ----
    w2pack_kernel<<<dim3(W2LD * D_ / 256), blk, 0, stream>>>(Wq, Wk, Xi, W2);
    bpack_kernel<<<dim3(D_ * PACKLD / 256), blk, 0, stream>>>(Xi, Wq, Wk, Bpk);
    t768_kernel<<<dim3(D_ * D_ / 256), blk, 0, stream>>>(dec_W, decT);
    t768_kernel<<<dim3(D_ * D_ / 256), blk, 0, stream>>>(enc_W, encT);
    mask_flags_kernel<<<dim3(1), dim3(64), 0, stream>>>(mask, flags);

    // ---- encode + build x ----
    patchify_kernel<<<dim3(B_ * NPATCH * PELEMS / 256), blk, 0, stream>>>(img, patch);
    mfma_gemm<0, false, true><<<dim3(D_ / 128, MPAD / 64), blk, 0, stream>>>(
        patch, PELEMS, encT, PELEMS, tok, D_, nullptr, enc_b, PELEMS);
    build_x_kernel<<<dim3(ROWS), blk, 0, stream>>>(tok, flags, cls, mtok, pos, x);

    // ---- energy-descent loop ----
    for (int step = 0; step < NSTEPS; ++step) {
        lnorm_kernel<<<dim3(ROWS), blk, 0, stream>>>(x, g, gamma, delta);
        // [qk | hid] = g @ [Wq|Wk|Xi]  (1D grid, temporal column-group swizzle)
        mfma_gemm<3, false, false><<<dim3((W2LD / 128) * (MPAD / 64)), blk, 0, stream>>>(
            g, D_, W2, D_, qkg, QKLD, pack, nullptr, D_);
        // S + softmax -> P, PT, kT, qT
        attn_pgq_kernel<<<dim3(B_ * HEADS_, 7), blk, 0, stream>>>(qkg, Pbuf, PTb, kT, qT);
        // Gq = P K, Gk = P^T Q  (MFMA) -> pack cols 3072..4607
        attn_pv_kernel<<<dim3(B_ * HEADS_, 2, 2), blk, 0, stream>>>(
            Pbuf, PTb, kT, qT, pack);
        // x += ALPHA * ([hid|Gq|Gk] @ [Xi|Wq|Wk]^T)  (split-K x4, atomic)
        mfma_gemm<4, false, false><<<dim3(D_ / 128, MPAD / 64, KSPLIT), blk, 0, stream>>>(
            pack, PACKLD, Bpk, PACKLD, x, D_, nullptr, nullptr, PACKLD / KSPLIT);
    }

    // ---- decode + unpatchify ----
    lnorm_kernel<<<dim3(ROWS), blk, 0, stream>>>(x, g, gamma, delta);
    mfma_gemm<0, false, true><<<dim3(D_ / 128, MPAD / 64), blk, 0, stream>>>(
        g, D_, decT, D_, decb, D_, nullptr, dec_b, D_);
    unpatch_kernel<<<dim3(B_ * C_ * H_ * W_ / 256), blk, 0, stream>>>(decb, out);
}

// Round 13
// 2253.933 us; speedup vs baseline: 1.0096x; 1.0096x over previous
//
#include <hip/hip_runtime.h>
#include <math.h>

// ---- problem constants ----
#define C_      3
#define H_      224
#define W_      224
#define KH_     14
#define KW_     14
#define NPATCH  196
#define PELEMS  768
#define D_      768
#define HEADS_  12
#define Y_      64
#define MHID    3072
#define NMASK   100
#define NSTEPS  12
#define ALPHA_  0.1f
#define BETA_   0.125f
#define EPS_    1e-5f
#define B_      16
#define NTOK    197
#define ROWS    (B_*NTOK)   /* 3152 real rows */
#define MPAD    3200        /* 50 * 64 */
#define QKLD    1536        /* fused q|k leading dim */
#define PACKLD  4608        /* hid(3072) | Gq(768) | Gk(768) */
#define W2LD    4608        /* qk(1536) | hid(3072) fused B rows */
#define PMP     228         /* LDS P pitch (fp32) */
#define PPITCH  224         /* global P/PT/kT/qT pitch (bf16), 7*32 */
#define KSPLIT  4           /* grad GEMM split-K (4608/4=1152=18*64) */

typedef short short8 __attribute__((ext_vector_type(8)));
typedef unsigned short ushort8 __attribute__((ext_vector_type(8)));
typedef float floatx4 __attribute__((ext_vector_type(4)));

__device__ __forceinline__ unsigned short f2bf(float f) {
    union { float f; unsigned u; } v; v.f = f;
    unsigned r = (v.u + 0x7FFFu + ((v.u >> 16) & 1u)) >> 16;
    return (unsigned short)r;
}
__device__ __forceinline__ float bf2f(unsigned short u) {
    union { unsigned u; float f; } v; v.u = ((unsigned)u) << 16;
    return v.f;
}

__device__ __forceinline__ void async_cp16(const void* g, void* l) {
    __builtin_amdgcn_global_load_lds(
        (const __attribute__((address_space(1))) unsigned int*)g,
        (__attribute__((address_space(3))) unsigned int*)l, 16, 0, 0);
}

// ---------------------------------------------------------------------------
// MFMA bf16 NT GEMM: C[M][N] = A(MxK bf16) @ B(NxK bf16)^T.
// 64x128 tile, BK=64/iter, DOUBLE-BUFFERED global_load_lds staging:
//   barrier -> issue stage(next pair) -> compute(current pair).
// The barrier's vmcnt(0) drain now waits on loads issued one full
// compute-phase earlier (mostly landed), instead of just-issued ones.
// (Register-prefetch staging spills to scratch — r8. FETCH ~103 MB is the
// 8-XCD floor: each XCD fetches A+B once — r12. Swizzles are neutral.)
// OUT_MODE: 0 = fp32 store, 1 = bf16 store,
//           3 = split epilogue: col<1536 -> Cout bf16 (ld QKLD), else relu ->
//               Cout2 bf16 (ld PACKLD, col-1536)
//           4 = split-K: koff = blockIdx.z*K, atomicAdd(Cout, ALPHA*v) fp32
template<int OUT_MODE, bool RELU, bool HAS_BIAS>
__global__ __launch_bounds__(256) void mfma_gemm(
    const unsigned short* __restrict__ A, int lda,
    const unsigned short* __restrict__ B, int ldb,
    void* __restrict__ Cout, int ldc, void* __restrict__ Cout2,
    const float* __restrict__ bias, int K)
{
    __shared__ alignas(16) unsigned short ldsA[2][2][64 * 32];
    __shared__ alignas(16) unsigned short ldsB[2][2][128 * 32];

    const int bx = blockIdx.x, by = blockIdx.y;
    const int koff = (OUT_MODE == 4) ? blockIdx.z * K : 0;

    const int t    = threadIdx.x;
    const int wave = t >> 6;
    const int lane = t & 63;
    const int row0 = by << 6;
    const int col0 = bx << 7;
    const int wm = (wave & 1) << 5;
    const int wn = (wave >> 1) << 6;
    const int r  = lane & 15;
    const int qd = lane >> 4;

    const unsigned short* Abase = A + (size_t)row0 * lda + koff;
    const unsigned short* Bbase = B + (size_t)col0 * ldb + koff;

    floatx4 acc[2][4];
#pragma unroll
    for (int i = 0; i < 2; ++i)
#pragma unroll
        for (int j = 0; j < 4; ++j)
            acc[i][j] = (floatx4){0.f, 0.f, 0.f, 0.f};

    const int crow = t >> 2;            // 0..63
    const int coff = (t & 3) << 3;      // {0,8,16,24} shorts

    auto stage = [&](int p, int k0) {
#pragma unroll
        for (int kb = 0; kb < 2; ++kb) {
            const int kk = k0 + kb * 32;
            async_cp16(Abase + (size_t)crow * lda + kk + coff,
                       ldsA[p][kb] + (wave << 9));
            async_cp16(Bbase + (size_t)crow * ldb + kk + coff,
                       ldsB[p][kb] + (wave << 9));
            async_cp16(Bbase + (size_t)(64 + crow) * ldb + kk + coff,
                       ldsB[p][kb] + 2048 + (wave << 9));
        }
    };

    stage(0, 0);
    int p = 0;
    for (int k0 = 0; k0 < K; k0 += 64) {
        __syncthreads();                    // drains pair-p loads (issued one
                                            // compute-phase ago) + LDS reuse
        if (k0 + 64 < K) stage(p ^ 1, k0 + 64);
#pragma unroll
        for (int kb = 0; kb < 2; ++kb) {
            short8 af[2], bfr[4];
#pragma unroll
            for (int i = 0; i < 2; ++i)
                af[i]  = *(const short8*)&ldsA[p][kb][(wm + (i << 4) + r) * 32 + (qd << 3)];
#pragma unroll
            for (int j = 0; j < 4; ++j)
                bfr[j] = *(const short8*)&ldsB[p][kb][(wn + (j << 4) + r) * 32 + (qd << 3)];
#pragma unroll
            for (int i = 0; i < 2; ++i)
#pragma unroll
                for (int j = 0; j < 4; ++j)
                    acc[i][j] = __builtin_amdgcn_mfma_f32_16x16x32_bf16(
                                    af[i], bfr[j], acc[i][j], 0, 0, 0);
        }
        p ^= 1;
    }

#pragma unroll
    for (int i = 0; i < 2; ++i) {
#pragma unroll
        for (int j = 0; j < 4; ++j) {
            int cc = col0 + wn + (j << 4) + r;
#pragma unroll
            for (int reg = 0; reg < 4; ++reg) {
                int rr = row0 + wm + (i << 4) + (qd << 2) + reg;
                float v = acc[i][j][reg];
                if (HAS_BIAS) v += bias[cc];
                if (RELU)     v = fmaxf(v, 0.f);
                if (OUT_MODE == 1)
                    ((unsigned short*)Cout)[(size_t)rr * ldc + cc] = f2bf(v);
                else if (OUT_MODE == 3) {
                    if (cc < QKLD)
                        ((unsigned short*)Cout)[(size_t)rr * QKLD + cc] = f2bf(v);
                    else
                        ((unsigned short*)Cout2)[(size_t)rr * PACKLD + (cc - QKLD)]
                            = f2bf(fmaxf(v, 0.f));
                } else if (OUT_MODE == 4)
                    atomicAdd(&((float*)Cout)[(size_t)rr * ldc + cc], ALPHA_ * v);
                else
                    ((float*)Cout)[(size_t)rr * ldc + cc] = v;
            }
        }
    }
}

// ---------------------------------------------------------------------------
// Attention A: per (bh, 32-q-row chunk): S = Q K^T via MFMA, softmax (beta in
// exp), write P[bh][n][m], PT[bh][m][n] (bf16, pitch 224, K-dims zeroed),
// plus the kT[y][m] / qT[y][n] slices for this block's m/n range.
__global__ __launch_bounds__(256) void attn_pgq_kernel(
    const unsigned short* __restrict__ qk,   // bf16 [MPAD][1536]
    unsigned short* __restrict__ P,          // [192][224][224]
    unsigned short* __restrict__ PT,         // [192][224][224]
    unsigned short* __restrict__ kT,         // [192][64][224]
    unsigned short* __restrict__ qT)         // [192][64][224]
{
    const int bh = blockIdx.x;
    const int h = bh % HEADS_, b = bh / HEADS_;
    const int n0 = blockIdx.y << 5;
    const int csz = (NTOK - n0 < 32) ? (NTOK - n0) : 32;
    const int t = threadIdx.x;
    const int lane = t & 63, wave = t >> 6;
    const int ln15 = lane & 15, quad = lane >> 4;

    __shared__ alignas(16) unsigned short KsS[208 * 72];  // K_h m-major
    __shared__ alignas(16) unsigned short QcS[32 * 72];   // Q chunk
    __shared__ alignas(16) float Pm[32 * PMP];            // S/P fp32

    const size_t rowbase = (size_t)(b * NTOK) * QKLD;
    const int hoff = h * 64;

    for (int idx = t; idx < NTOK * 8; idx += 256) {
        int m = idx >> 3, c8 = idx & 7;
        *(uint4*)&KsS[m * 72 + c8 * 8] =
            *(const uint4*)&qk[rowbase + (size_t)m * QKLD + 768 + hoff + c8 * 8];
    }
    for (int idx = t; idx < 88; idx += 256) {
        int m = 197 + (idx >> 3), c8 = idx & 7;
        *(uint4*)&KsS[m * 72 + c8 * 8] = (uint4){0, 0, 0, 0};
    }
    for (int idx = t; idx < csz * 8; idx += 256) {
        int nn = idx >> 3, c8 = idx & 7;
        *(uint4*)&QcS[nn * 72 + c8 * 8] =
            *(const uint4*)&qk[rowbase + (size_t)(n0 + nn) * QKLD + hoff + c8 * 8];
    }
    __syncthreads();

    // ---- S = Q K^T via MFMA ----
    {
        short8 aq[2][2];
#pragma unroll
        for (int mt = 0; mt < 2; ++mt)
#pragma unroll
            for (int kb = 0; kb < 2; ++kb)
                aq[mt][kb] = *(const short8*)
                    &QcS[(mt * 16 + ln15) * 72 + kb * 32 + quad * 8];

        for (int nt = wave; nt < 13; nt += 4) {
            short8 b0 = *(const short8*)&KsS[(nt * 16 + ln15) * 72 + quad * 8];
            short8 b1 = *(const short8*)&KsS[(nt * 16 + ln15) * 72 + 32 + quad * 8];
            floatx4 s0 = (floatx4){0.f, 0.f, 0.f, 0.f};
            floatx4 s1 = (floatx4){0.f, 0.f, 0.f, 0.f};
            s0 = __builtin_amdgcn_mfma_f32_16x16x32_bf16(aq[0][0], b0, s0, 0, 0, 0);
            s0 = __builtin_amdgcn_mfma_f32_16x16x32_bf16(aq[0][1], b1, s0, 0, 0, 0);
            s1 = __builtin_amdgcn_mfma_f32_16x16x32_bf16(aq[1][0], b0, s1, 0, 0, 0);
            s1 = __builtin_amdgcn_mfma_f32_16x16x32_bf16(aq[1][1], b1, s1, 0, 0, 0);
#pragma unroll
            for (int reg = 0; reg < 4; ++reg) {
                Pm[(quad * 4 + reg) * PMP + nt * 16 + ln15]        = s0[reg];
                Pm[(16 + quad * 4 + reg) * PMP + nt * 16 + ln15]   = s1[reg];
            }
        }
    }

    // ---- kT / qT slices (reads staged LDS, independent of Pm) ----
    {
        const int yq = t & 63;
        const int mg = t >> 6;          // 0..3, 8 m each
        unsigned short* kTd = kT + (size_t)bh * 64 * PPITCH + (size_t)yq * PPITCH;
        unsigned short* qTd = qT + (size_t)bh * 64 * PPITCH + (size_t)yq * PPITCH;
#pragma unroll
        for (int c = 0; c < 4; ++c) {
            int mm = n0 + mg * 8 + 2 * c;
            unsigned lo = (mm     < 208) ? (unsigned)KsS[(mm    ) * 72 + yq] : 0u;
            unsigned hi = (mm + 1 < 208) ? (unsigned)KsS[(mm + 1) * 72 + yq] : 0u;
            *(unsigned*)&kTd[mm] = lo | (hi << 16);
        }
#pragma unroll
        for (int c = 0; c < 4; ++c) {
            int nn = mg * 8 + 2 * c;
            unsigned lo = (nn     < csz) ? (unsigned)QcS[(nn    ) * 72 + yq] : 0u;
            unsigned hi = (nn + 1 < csz) ? (unsigned)QcS[(nn + 1) * 72 + yq] : 0u;
            *(unsigned*)&qTd[n0 + nn] = lo | (hi << 16);
        }
    }
    __syncthreads();

    // ---- softmax rows (beta applied inside exp) ----
    for (int nn = wave; nn < csz; nn += 4) {
        float v0 = Pm[nn * PMP + lane];
        float v1 = (lane +  64 < NTOK) ? Pm[nn * PMP + lane +  64] : -1e30f;
        float v2 = (lane + 128 < NTOK) ? Pm[nn * PMP + lane + 128] : -1e30f;
        float v3 = (lane + 192 < NTOK) ? Pm[nn * PMP + lane + 192] : -1e30f;
        float mx = fmaxf(fmaxf(v0, v1), fmaxf(v2, v3));
#pragma unroll
        for (int o = 32; o > 0; o >>= 1) mx = fmaxf(mx, __shfl_xor(mx, o, 64));
        float e0 = __expf((v0 - mx) * BETA_);
        float e1 = (lane +  64 < NTOK) ? __expf((v1 - mx) * BETA_) : 0.f;
        float e2 = (lane + 128 < NTOK) ? __expf((v2 - mx) * BETA_) : 0.f;
        float e3 = (lane + 192 < NTOK) ? __expf((v3 - mx) * BETA_) : 0.f;
        float s = e0 + e1 + e2 + e3;
#pragma unroll
        for (int o = 32; o > 0; o >>= 1) s += __shfl_xor(s, o, 64);
        float inv = 1.0f / s;
        Pm[nn * PMP + lane] = e0 * inv;
        if (lane +  64 < NTOK) Pm[nn * PMP + lane +  64] = e1 * inv;
        if (lane + 128 < NTOK) Pm[nn * PMP + lane + 128] = e2 * inv;
        if (lane + 192 < NTOK) Pm[nn * PMP + lane + 192] = e3 * inv;
    }
    __syncthreads();

    // ---- write P rows (m-pads zero) ----
    if (t < PPITCH) {
        for (int nn = 0; nn < csz; ++nn) {
            unsigned short v = (t < NTOK) ? f2bf(Pm[nn * PMP + t]) : (unsigned short)0;
            P[((size_t)bh * PPITCH + n0 + nn) * PPITCH + t] = v;
        }
    }
    // ---- write PT cols (32-wide n-chunk; nn>=csz and m>=197 zeroed) ----
    if (t < PPITCH) {
        unsigned short* drow = &PT[((size_t)bh * PPITCH + t) * PPITCH + n0];
        bool mreal = (t < NTOK);
#pragma unroll
        for (int c = 0; c < 16; ++c) {
            unsigned lo = (mreal && 2 * c     < csz) ? f2bf(Pm[(2 * c    ) * PMP + t]) : 0u;
            unsigned hi = (mreal && 2 * c + 1 < csz) ? f2bf(Pm[(2 * c + 1) * PMP + t]) : 0u;
            *(unsigned*)&drow[2 * c] = lo | (hi << 16);
        }
    }
}

// ---------------------------------------------------------------------------
// Attention B (MFMA): grid (192, 2, 2).
// sel=0: Gq[n][y] = sum_m P[n][m] kT[y][m]  -> pack cols 3072+
// sel=1: Gk[m][y] = sum_n PT[m][n] qT[y][n] -> pack cols 3840+
__global__ __launch_bounds__(256) void attn_pv_kernel(
    const unsigned short* __restrict__ P,
    const unsigned short* __restrict__ PT,
    const unsigned short* __restrict__ kT,
    const unsigned short* __restrict__ qT,
    unsigned short* __restrict__ pack)
{
    const int bh = blockIdx.x;
    const int h = bh % HEADS_, b = bh / HEADS_;
    const int sel = blockIdx.y;
    const int mbase = blockIdx.z * 112;
    const int t = threadIdx.x;
    const int lane = t & 63, wave = t >> 6;
    const int ln15 = lane & 15, quad = lane >> 4;

    const unsigned short* Abase = (sel ? PT : P) + (size_t)bh * PPITCH * PPITCH;
    const unsigned short* Bv    = (sel ? qT : kT) + (size_t)bh * 64 * PPITCH;
    const int colbase = sel ? 3840 : 3072;

    __shared__ alignas(16) unsigned short Bs[64 * 232];
    for (int idx = t; idx < 64 * 28; idx += 256) {
        int y = idx / 28, c = idx % 28;
        *(uint4*)&Bs[y * 232 + c * 8] = *(const uint4*)&Bv[(size_t)y * PPITCH + c * 8];
    }
    __syncthreads();

    floatx4 acc[7];
#pragma unroll
    for (int i = 0; i < 7; ++i) acc[i] = (floatx4){0.f, 0.f, 0.f, 0.f};

    for (int kb = 0; kb < 7; ++kb) {
        short8 bf = *(const short8*)&Bs[(wave * 16 + ln15) * 232 + kb * 32 + quad * 8];
#pragma unroll
        for (int i = 0; i < 7; ++i) {
            short8 af = *(const short8*)
                &Abase[(size_t)(mbase + i * 16 + ln15) * PPITCH + kb * 32 + quad * 8];
            acc[i] = __builtin_amdgcn_mfma_f32_16x16x32_bf16(af, bf, acc[i], 0, 0, 0);
        }
    }

    const int coln = colbase + h * 64 + wave * 16 + ln15;
#pragma unroll
    for (int i = 0; i < 7; ++i) {
#pragma unroll
        for (int reg = 0; reg < 4; ++reg) {
            int rowm = mbase + i * 16 + quad * 4 + reg;
            if (rowm < NTOK)
                pack[(size_t)(b * NTOK + rowm) * PACKLD + coln] = f2bf(acc[i][reg]);
        }
    }
}

// ---------------------------------------------------------------------------
// setup conversions
__global__ __launch_bounds__(256) void w2pack_kernel(const float* __restrict__ Wq,
                                                     const float* __restrict__ Wk,
                                                     const float* __restrict__ Xi,
                                                     unsigned short* __restrict__ out)
{
    int idx = blockIdx.x * 256 + threadIdx.x;          // n*768 + d
    int d = idx % D_, n = idx / D_;
    float v;
    if (n < 768)       v = Wq[((size_t)(n >> 6) * D_ + d) * Y_ + (n & 63)];
    else if (n < 1536) { int e = n - 768; v = Wk[((size_t)(e >> 6) * D_ + d) * Y_ + (e & 63)]; }
    else               v = Xi[(size_t)d * MHID + (n - 1536)];
    out[idx] = f2bf(v);
}

__global__ __launch_bounds__(256) void bpack_kernel(const float* __restrict__ Xi,
                                                    const float* __restrict__ Wq,
                                                    const float* __restrict__ Wk,
                                                    unsigned short* __restrict__ out)
{
    int idx = blockIdx.x * 256 + threadIdx.x;          // d*4608 + c
    int c = idx % PACKLD, d = idx / PACKLD;
    float v;
    if (c < 3072)       v = Xi[(size_t)d * MHID + c];
    else if (c < 3840)  { int e = c - 3072; v = Wq[((size_t)(e >> 6) * D_ + d) * Y_ + (e & 63)]; }
    else                { int e = c - 3840; v = Wk[((size_t)(e >> 6) * D_ + d) * Y_ + (e & 63)]; }
    out[idx] = f2bf(v);
}

__global__ __launch_bounds__(256) void t768_kernel(const float* __restrict__ in,
                                                   unsigned short* __restrict__ out)
{
    int idx = blockIdx.x * 256 + threadIdx.x;          // n*768 + k
    int k = idx % D_, n = idx / D_;
    out[idx] = f2bf(in[(size_t)k * D_ + n]);
}

// ---------------------------------------------------------------------------
__global__ void mask_flags_kernel(const int* __restrict__ mask, int* __restrict__ flags)
{
    int b = threadIdx.x;
    if (b >= B_) return;
    const int* mb = mask + b * NPATCH;
    int* fb = flags + b * NPATCH;
    int cnt = 0;
    for (int n = 0; n < NPATCH; ++n) {
        int mv = mb[n];
        fb[n] = (mv == 1 && cnt < NMASK) ? 1 : 0;
        cnt += (mv == 1);
    }
    if (cnt < NMASK) fb[0] = 1;
}

__global__ __launch_bounds__(256) void patchify_kernel(const float* __restrict__ img,
                                                       unsigned short* __restrict__ patch)
{
    int idx = blockIdx.x * 256 + threadIdx.x;          // row*768 + e
    int e = idx % PELEMS, row = idx / PELEMS;
    int b = row / NPATCH, n = row % NPATCH;
    int kh = n / KW_, kw = n % KW_;
    int c = e >> 8, p = (e >> 4) & 15, q2 = e & 15;
    patch[idx] = f2bf(img[(((size_t)b * C_ + c) * H_ + kh * 16 + p) * W_ + kw * 16 + q2]);
}

__global__ __launch_bounds__(256) void build_x_kernel(const float* __restrict__ tok,
                                                      const int* __restrict__ flags,
                                                      const float* __restrict__ cls,
                                                      const float* __restrict__ mtok,
                                                      const float* __restrict__ pos,
                                                      float* __restrict__ x)
{
    int row = blockIdx.x;
    int b = row / NTOK, rr = row % NTOK;
    int tid = threadIdx.x;
#pragma unroll
    for (int i = 0; i < 3; ++i) {
        int d = tid + (i << 8);
        float v;
        if (rr == 0) v = cls[d];
        else {
            int n = rr - 1;
            v = flags[b * NPATCH + n] ? mtok[d]
                                      : tok[((size_t)b * NPATCH + n) * D_ + d];
        }
        x[(size_t)row * D_ + d] = v + pos[(size_t)rr * D_ + d];
    }
}

__global__ __launch_bounds__(256) void lnorm_kernel(const float* __restrict__ x,
                                                    unsigned short* __restrict__ g,
                                                    const float* __restrict__ gamma,
                                                    const float* __restrict__ delta)
{
    int row = blockIdx.x, tid = threadIdx.x;
    const float* xr = x + (size_t)row * D_;
    float v0 = xr[tid], v1 = xr[tid + 256], v2 = xr[tid + 512];

    __shared__ float red[256];
    red[tid] = v0 + v1 + v2;
    __syncthreads();
    for (int off = 128; off > 0; off >>= 1) {
        if (tid < off) red[tid] += red[tid + off];
        __syncthreads();
    }
    float mean = red[0] * (1.0f / D_);
    __syncthreads();
    float a0 = v0 - mean, a1 = v1 - mean, a2 = v2 - mean;
    red[tid] = a0 * a0 + a1 * a1 + a2 * a2;
    __syncthreads();
    for (int off = 128; off > 0; off >>= 1) {
        if (tid < off) red[tid] += red[tid + off];
        __syncthreads();
    }
    float var = red[0] * (1.0f / D_);
    float inv = gamma[0] / sqrtf(var + EPS_);
    unsigned short* gr = g + (size_t)row * D_;
    gr[tid]       = f2bf(a0 * inv + delta[tid]);
    gr[tid + 256] = f2bf(a1 * inv + delta[tid + 256]);
    gr[tid + 512] = f2bf(a2 * inv + delta[tid + 512]);
}

// ---------------------------------------------------------------------------
__global__ __launch_bounds__(256) void unpatch_kernel(const float* __restrict__ dec,
                                                      float* __restrict__ out)
{
    int idx = blockIdx.x * 256 + threadIdx.x;
    int ww = idx % W_;
    int t2 = idx / W_;
    int hh = t2 % H_;
    int t3 = t2 / H_;
    int c  = t3 % C_;
    int b  = t3 / C_;
    int kh = hh >> 4, p = hh & 15, kw = ww >> 4, q2 = ww & 15;
    int n = kh * KW_ + kw;
    int e = (c << 8) + (p << 4) + q2;
    out[idx] = dec[((size_t)b * NTOK + 1 + n) * D_ + e];
}

// ---------------------------------------------------------------------------
extern "C" void kernel_launch(void* const* d_in, const int* in_sizes, int n_in,
                              void* d_out, int out_size, void* d_ws, size_t ws_size,
                              hipStream_t stream)
{
    const float* img   = (const float*)d_in[0];
    const int*   mask  = (const int*)d_in[1];
    const float* enc_W = (const float*)d_in[2];
    const float* enc_b = (const float*)d_in[3];
    const float* dec_W = (const float*)d_in[4];
    const float* dec_b = (const float*)d_in[5];
    const float* cls   = (const float*)d_in[6];
    const float* mtok  = (const float*)d_in[7];
    const float* pos   = (const float*)d_in[8];
    const float* Wq    = (const float*)d_in[9];
    const float* Wk    = (const float*)d_in[10];
    const float* Xi    = (const float*)d_in[11];
    const float* gamma = (const float*)d_in[12];
    const float* delta = (const float*)d_in[13];
    float* out = (float*)d_out;

    float* ws = (float*)d_ws;
    size_t off = 0;
    auto alloc = [&](size_t nfloats) {
        off = (off + 63) & ~(size_t)63;
        float* p = ws + off; off += nfloats; return p;
    };
    float*          x    = alloc((size_t)MPAD * D_);                  // fp32
    unsigned short* g    = (unsigned short*)alloc((size_t)MPAD * D_ / 2);
    // qk bf16 [MPAD][1536]; bytes reused as dec fp32 [MPAD][768] at the end
    unsigned short* qkg  = (unsigned short*)alloc((size_t)MPAD * QKLD / 2);
    float*          decb = (float*)qkg;
    unsigned short* pack = (unsigned short*)alloc((size_t)MPAD * PACKLD / 2);
    unsigned short* Pbuf = (unsigned short*)alloc((size_t)192 * PPITCH * PPITCH / 2);
    unsigned short* PTb  = (unsigned short*)alloc((size_t)192 * PPITCH * PPITCH / 2);
    unsigned short* kT   = (unsigned short*)alloc((size_t)192 * 64 * PPITCH / 2);
    unsigned short* qT   = (unsigned short*)alloc((size_t)192 * 64 * PPITCH / 2);
    unsigned short* W2   = (unsigned short*)alloc((size_t)W2LD * D_ / 2);
    unsigned short* Bpk  = (unsigned short*)alloc((size_t)D_ * PACKLD / 2);
    unsigned short* decT = (unsigned short*)alloc((size_t)D_ * D_ / 2);
    unsigned short* encT = (unsigned short*)alloc((size_t)D_ * D_ / 2);
    int*            flags = (int*)alloc(B_ * NPATCH);
    // setup-phase overlays inside pack (dead until first hid GEMM)
    unsigned short* patch = pack;                                // MPAD x 768 bf16
    float*          tok   = (float*)(pack + (size_t)MPAD * D_);  // MPAD x 768 fp32

    const dim3 blk(256);

    // ---- one-time packs ----
    w2pack_kernel<<<dim3(W2LD * D_ / 256), blk, 0, stream>>>(Wq, Wk, Xi, W2);
    bpack_kernel<<<dim3(D_ * PACKLD / 256), blk, 0, stream>>>(Xi, Wq, Wk, Bpk);
    t768_kernel<<<dim3(D_ * D_ / 256), blk, 0, stream>>>(dec_W, decT);
    t768_kernel<<<dim3(D_ * D_ / 256), blk, 0, stream>>>(enc_W, encT);
    mask_flags_kernel<<<dim3(1), dim3(64), 0, stream>>>(mask, flags);

    // ---- encode + build x ----
    patchify_kernel<<<dim3(B_ * NPATCH * PELEMS / 256), blk, 0, stream>>>(img, patch);
    mfma_gemm<0, false, true><<<dim3(D_ / 128, MPAD / 64), blk, 0, stream>>>(
        patch, PELEMS, encT, PELEMS, tok, D_, nullptr, enc_b, PELEMS);
    build_x_kernel<<<dim3(ROWS), blk, 0, stream>>>(tok, flags, cls, mtok, pos, x);

    // ---- energy-descent loop ----
    for (int step = 0; step < NSTEPS; ++step) {
        lnorm_kernel<<<dim3(ROWS), blk, 0, stream>>>(x, g, gamma, delta);
        // [qk | hid] = g @ [Wq|Wk|Xi]  (split epilogue, 2D grid)
        mfma_gemm<3, false, false><<<dim3(W2LD / 128, MPAD / 64), blk, 0, stream>>>(
            g, D_, W2, D_, qkg, QKLD, pack, nullptr, D_);
        // S + softmax -> P, PT, kT, qT
        attn_pgq_kernel<<<dim3(B_ * HEADS_, 7), blk, 0, stream>>>(qkg, Pbuf, PTb, kT, qT);
        // Gq = P K, Gk = P^T Q  (MFMA) -> pack cols 3072..4607
        attn_pv_kernel<<<dim3(B_ * HEADS_, 2, 2), blk, 0, stream>>>(
            Pbuf, PTb, kT, qT, pack);
        // x += ALPHA * ([hid|Gq|Gk] @ [Xi|Wq|Wk]^T)  (split-K x4, atomic)
        mfma_gemm<4, false, false><<<dim3(D_ / 128, MPAD / 64, KSPLIT), blk, 0, stream>>>(
            pack, PACKLD, Bpk, PACKLD, x, D_, nullptr, nullptr, PACKLD / KSPLIT);
    }

    // ---- decode + unpatchify ----
    lnorm_kernel<<<dim3(ROWS), blk, 0, stream>>>(x, g, gamma, delta);
    mfma_gemm<0, false, true><<<dim3(D_ / 128, MPAD / 64), blk, 0, stream>>>(
        g, D_, decT, D_, decb, D_, nullptr, dec_b, D_);
    unpatch_kernel<<<dim3(B_ * C_ * H_ * W_ / 256), blk, 0, stream>>>(decb, out);
}